// Round 8
// baseline (926.113 us; speedup 1.0000x reference)
//
#include <hip/hip_runtime.h>
#include <math.h>
#include <stdint.h>

namespace {

constexpr int Bc = 8, Sc = 1024, Dc = 512, Hc = 8, FFc = 2048, Lc = 4, OUTc = 6;
constexpr int QS = 1536;

typedef __attribute__((ext_vector_type(8))) short  bf16x8;
typedef __attribute__((ext_vector_type(4))) float  f32x4;

__device__ __forceinline__ void ld4(float d[4], const float* s) {
    float4 t = *(const float4*)s;
    d[0] = t.x; d[1] = t.y; d[2] = t.z; d[3] = t.w;
}
__device__ __forceinline__ float bf2f_u(unsigned short u) {
    union { uint32_t i; float f; } c; c.i = ((uint32_t)u) << 16; return c.f;
}
__device__ __forceinline__ float bf2f_s(short u) {
    union { uint32_t i; float f; } c; c.i = ((uint32_t)(unsigned short)u) << 16; return c.f;
}
__device__ __forceinline__ unsigned short f2bf(float f) {   // RNE
    union { float f; uint32_t i; } c; c.f = f;
    uint32_t r = c.i + 0x7FFF + ((c.i >> 16) & 1);
    return (unsigned short)(r >> 16);
}
__device__ __forceinline__ unsigned short f2bf_fast(float f) {
    union { float f; uint32_t i; } c; c.f = f;
    return (unsigned short)((c.i + 0x8000u) >> 16);
}

#define GLDS16(gp, lp) __builtin_amdgcn_global_load_lds(                      \
    (const __attribute__((address_space(1))) uint32_t*)(gp),                  \
    (__attribute__((address_space(3))) uint32_t*)(lp), 16, 0, 0)

// ---------------- weight transposes+casts + LN-fold + c1/c2 --------------
// out[n][k] = bf16(gamma[k]*in[k][n]) for qkv/W1; plain for Wo/W2.
// c1[n] += sum_k gamma[k] in[k][n]; c2[n] += sum_k beta[k] in[k][n].
__global__ __launch_bounds__(256) void castAll(
    const float* __restrict__ Wq, const float* __restrict__ Wk,
    const float* __restrict__ Wv, const float* __restrict__ Wo,
    const float* __restrict__ W1, const float* __restrict__ W2,
    const float* __restrict__ gp, const float* __restrict__ bp,
    const float* __restrict__ g1, const float* __restrict__ b1,
    const float* __restrict__ g2, const float* __restrict__ b2,
    unsigned short* __restrict__ qkvT, unsigned short* __restrict__ WoT,
    unsigned short* __restrict__ W1T, unsigned short* __restrict__ W2T,
    float* __restrict__ c1qkv, float* __restrict__ c2qkv,
    float* __restrict__ c1w1, float* __restrict__ c2w1)
{
    const int t = blockIdx.x;
    const float* in; unsigned short* out; int K, N, k0, n0;
    bool fold = false;
    const float *gamma = nullptr, *beta = nullptr;
    float *cv1 = nullptr, *cv2 = nullptr;
    if (t < 1024) {            // qkvo: 16 mats x 8x8 tiles of 512x512
        const int mat = t >> 6, l = mat >> 2, w = mat & 3;
        K = 512; N = 512;
        k0 = ((t >> 3) & 7) << 6; n0 = (t & 7) << 6;
        const float* ws4[4] = {Wq, Wk, Wv, Wo};
        in = ws4[w] + (size_t)l * 512 * 512;
        if (w < 3) {
            out = qkvT + (size_t)l * QS * 512 + (size_t)w * 512 * 512;
            fold = true;
            gamma = (l == 0) ? gp : g2 + (size_t)(l - 1) * 512;
            beta  = (l == 0) ? bp : b2 + (size_t)(l - 1) * 512;
            cv1 = c1qkv + (size_t)l * QS + w * 512;
            cv2 = c2qkv + (size_t)l * QS + w * 512;
        } else {
            out = WoT + (size_t)l * 512 * 512;
        }
    } else if (t < 2048) {     // W1
        const int u = t - 1024, l = u >> 8;
        K = 512; N = 2048;
        k0 = ((u >> 5) & 7) << 6; n0 = (u & 31) << 6;
        in = W1 + (size_t)l * 512 * 2048;
        out = W1T + (size_t)l * 2048 * 512;
        fold = true;
        gamma = g1 + (size_t)l * 512; beta = b1 + (size_t)l * 512;
        cv1 = c1w1 + (size_t)l * 2048; cv2 = c2w1 + (size_t)l * 2048;
    } else {                   // W2
        const int u = t - 2048, l = u >> 8;
        K = 2048; N = 512;
        k0 = ((u >> 3) & 31) << 6; n0 = (u & 7) << 6;
        in = W2 + (size_t)l * 2048 * 512;
        out = W2T + (size_t)l * 512 * 2048;
    }
    __shared__ float tbuf[64][65];
    __shared__ float gls[64], bls[64];
    const int c = threadIdx.x & 63, r4 = threadIdx.x >> 6;
    if (fold && threadIdx.x < 64) {
        gls[threadIdx.x] = gamma[k0 + threadIdx.x];
        bls[threadIdx.x] = beta[k0 + threadIdx.x];
    }
    #pragma unroll
    for (int it = 0; it < 16; ++it) {
        const int r = (it << 2) + r4;
        tbuf[r][c] = in[(size_t)(k0 + r) * N + n0 + c];
    }
    __syncthreads();
    #pragma unroll
    for (int it = 0; it < 16; ++it) {
        const int r = (it << 2) + r4;           // n index
        float v = tbuf[c][r];
        if (fold) v *= gls[c];
        out[(size_t)(n0 + r) * K + k0 + c] = f2bf(v);
    }
    if (fold && threadIdx.x < 64) {
        float a1 = 0.f, a2 = 0.f;
        #pragma unroll
        for (int cc = 0; cc < 64; ++cc) {
            const float w = tbuf[cc][threadIdx.x];
            a1 = fmaf(gls[cc], w, a1);
            a2 = fmaf(bls[cc], w, a2);
        }
        atomicAdd(cv1 + n0 + threadIdx.x, a1);
        atomicAdd(cv2 + n0 + threadIdx.x, a2);
    }
}

// ---------------- proj + positional encoding (raw out + stats) -----------
__global__ __launch_bounds__(256) void proj_pe(
    const float* __restrict__ x, const float* __restrict__ Wproj,
    const float* __restrict__ bproj, unsigned short* __restrict__ res,
    float* __restrict__ stats, float* __restrict__ notpad,
    float* __restrict__ maskadd)
{
    const int wave = threadIdx.x >> 6, lane = threadIdx.x & 63;
    const int tok = (blockIdx.x << 2) + wave;
    const int s = tok & (Sc - 1);
    const float x0 = x[tok * 3 + 0], x1 = x[tok * 3 + 1], x2 = x[tok * 3 + 2];
    if (lane == 0) {
        const bool pad = (fabsf(x0) + fabsf(x1) + fabsf(x2) == 0.0f);
        notpad[tok]  = pad ? 0.0f : 1.0f;
        maskadd[tok] = pad ? -1e30f : 0.0f;
    }
    const float c = -logf(10000.0f) / (float)Dc;
    const int d0 = lane << 3;
    float sum = 0.f, sumsq = 0.f;
    bf16x8 rb;
    #pragma unroll
    for (int j = 0; j < 8; ++j) {
        const int d = d0 + j;
        float val = fmaf(x0, Wproj[d],
                    fmaf(x1, Wproj[Dc + d],
                    fmaf(x2, Wproj[2 * Dc + d], bproj[d])));
        const float arg = (float)s * expf((float)(d & ~1) * c);
        val += (d & 1) ? cosf(arg) : sinf(arg);
        rb[j] = (short)f2bf(val);
        const float rv = bf2f_s(rb[j]);
        sum += rv; sumsq += rv * rv;
    }
    *(bf16x8*)(res + (size_t)tok * Dc + d0) = rb;
    #pragma unroll
    for (int m = 1; m < 64; m <<= 1) {
        sum   += __shfl_xor(sum, m, 64);
        sumsq += __shfl_xor(sumsq, m, 64);
    }
    if (lane == 0) {
        stats[(size_t)tok * 32 + 0] = sum;
        stats[(size_t)tok * 32 + 1] = sumsq;
    }
}

// ---------------- bf16 MFMA GEMM, LN folded into epilogues ---------------
// EPI 3 = qkv (affine via c1/c2; q*qsc; v transposed to vT)
// EPI 1 = W1  (affine via c1/c2; silu)
// EPI 4/5 = Wo/W2 (delta + on-the-fly LN(resIn) add; write raw res + stats)
template<int EPI, int NT>
__global__ __launch_bounds__(256) void gemm_bf16(
    const unsigned short* __restrict__ A, const unsigned short* __restrict__ Bt,
    void* __restrict__ Cv, void* __restrict__ Cv2,
    const float* __restrict__ statsIn, int npart,
    const float* __restrict__ c1, const float* __restrict__ c2,
    const unsigned short* __restrict__ resIn,
    const float* __restrict__ gcol, const float* __restrict__ bcol,
    float* __restrict__ partOut, int M, int N, int K)
{
    constexpr int JN = NT / 32;
    constexpr int TR = 140;
    constexpr int ABsz = 128 * 64 + NT * 64;
    constexpr int SMsz = (EPI == 3 && 128 * TR > ABsz) ? 128 * TR : ABsz;
    __shared__ unsigned short smem[SMsz];
    __shared__ float muS[128], rsS[128];
    unsigned short* As = smem;
    unsigned short* Bs = smem + 128 * 64;
    const int tid = threadIdx.x;
    const int wave = tid >> 6, lane = tid & 63;
    const int m0 = blockIdx.y << 7;
    const int n0 = blockIdx.x * NT;
    const int wm = (wave >> 1) << 6;
    const int wn = (wave & 1) * (NT / 2);
    const int l15 = lane & 15;
    const int lg  = lane >> 4;
    const int grow  = lane >> 3;
    const int gcolk = ((lane & 7) ^ grow) << 3;

    f32x4 acc[4][JN] = {};

    for (int k0 = 0; k0 < K; k0 += 64) {
        __syncthreads();
        #pragma unroll
        for (int t = 0; t < 4; ++t) {
            const int rb = (t << 5) + (wave << 3);
            GLDS16(A + (size_t)(m0 + rb + grow) * K + k0 + gcolk, &As[rb * 64]);
        }
        #pragma unroll
        for (int t = 0; t < NT / 32; ++t) {
            const int rb = (t << 5) + (wave << 3);
            GLDS16(Bt + (size_t)(n0 + rb + grow) * K + k0 + gcolk, &Bs[rb * 64]);
        }
        __syncthreads();
        #pragma unroll
        for (int h = 0; h < 2; ++h) {
            const int sw = (((h << 2) + lg) ^ (l15 & 7)) << 3;
            bf16x8 af[4], bfr[JN];
            #pragma unroll
            for (int i = 0; i < 4; ++i)
                af[i] = *(const bf16x8*)&As[(wm + (i << 4) + l15) * 64 + sw];
            #pragma unroll
            for (int j = 0; j < JN; ++j)
                bfr[j] = *(const bf16x8*)&Bs[(wn + (j << 4) + l15) * 64 + sw];
            #pragma unroll
            for (int i = 0; i < 4; ++i)
                #pragma unroll
                for (int j = 0; j < JN; ++j)
                    acc[i][j] = __builtin_amdgcn_mfma_f32_16x16x32_bf16(
                        af[i], bfr[j], acc[i][j], 0, 0, 0);
        }
    }

    // ---- stage per-row (mu, rstd) of the input-stats rows -----------------
    __syncthreads();
    if (tid < 128) {
        float s1 = 0.f, s2 = 0.f;
        const float* pr = statsIn + (size_t)(m0 + tid) * 32;
        for (int p = 0; p < npart; ++p) { s1 += pr[2 * p]; s2 += pr[2 * p + 1]; }
        const float mu = s1 * (1.0f / 512.0f);
        muS[tid] = mu;
        rsS[tid] = rsqrtf(s2 * (1.0f / 512.0f) - mu * mu + 1e-5f);
    }
    __syncthreads();

    if constexpr (EPI == 3 || EPI == 1) {
        float c1v[JN], c2v[JN];
        const int ccol0 = n0 + wn + l15;
        #pragma unroll
        for (int j = 0; j < JN; ++j) {
            c1v[j] = c1[ccol0 + (j << 4)];
            c2v[j] = c2[ccol0 + (j << 4)];
        }
        if constexpr (EPI == 3) {
            if (n0 >= 1024) {   // V: affine then transpose via LDS
                unsigned short* Tr = smem;
                #pragma unroll
                for (int i = 0; i < 4; ++i)
                    #pragma unroll
                    for (int j = 0; j < JN; ++j)
                        #pragma unroll
                        for (int r = 0; r < 4; ++r) {
                            const int lr = wm + (i << 4) + (lg << 2) + r;
                            const float v = rsS[lr] * (acc[i][j][r] - muS[lr] * c1v[j]) + c2v[j];
                            Tr[(wn + (j << 4) + l15) * TR + lr] = f2bf(v);
                        }
                __syncthreads();
                const int bb = m0 >> 10, s0 = m0 & 1023;
                #pragma unroll
                for (int it = 0; it < 8; ++it) {
                    const int idx = (it << 8) + tid;
                    const int ln = idx >> 4, lmc = (idx & 15) << 3;
                    const int gcol2 = n0 - 1024 + ln;
                    const int head = gcol2 >> 6, dh = gcol2 & 63;
                    *(bf16x8*)((unsigned short*)Cv2 +
                        (size_t)((((bb << 3) + head) << 6) + dh) * 1024 + s0 + lmc) =
                        *(const bf16x8*)&smem[ln * TR + lmc];
                }
                return;
            }
        }
        const float qsc = 0.125f * 1.44269504f;
        #pragma unroll
        for (int i = 0; i < 4; ++i)
            #pragma unroll
            for (int j = 0; j < JN; ++j)
                #pragma unroll
                for (int r = 0; r < 4; ++r) {
                    const int lr = wm + (i << 4) + (lg << 2) + r;
                    const int row = m0 + lr;
                    const int col = ccol0 + (j << 4);
                    float v = rsS[lr] * (acc[i][j][r] - muS[lr] * c1v[j]) + c2v[j];
                    if (EPI == 3) {
                        if (n0 < 512) v *= qsc;
                        ((unsigned short*)Cv)[(size_t)row * 1024 + col] = f2bf(v);
                    } else {
                        v = v / (1.0f + expf(-v));
                        ((unsigned short*)Cv)[(size_t)row * N + col] = f2bf(v);
                    }
                }
    } else {   // EPI 4/5: res_new = LN(resIn) + acc; write + stats partials
        float gv[JN], bv[JN];
        const int ccol0 = n0 + wn + l15;
        #pragma unroll
        for (int j = 0; j < JN; ++j) {
            gv[j] = gcol[ccol0 + (j << 4)];
            bv[j] = bcol[ccol0 + (j << 4)];
        }
        const int slot = (blockIdx.x << 1) | (wave & 1);
        #pragma unroll
        for (int i = 0; i < 4; ++i)
            #pragma unroll
            for (int r = 0; r < 4; ++r) {
                const int lr = wm + (i << 4) + (lg << 2) + r;
                const int row = m0 + lr;
                float s1 = 0.f, s2 = 0.f;
                #pragma unroll
                for (int j = 0; j < JN; ++j) {
                    const int col = ccol0 + (j << 4);
                    const float hp = bf2f_u(resIn[(size_t)row * 512 + col]);
                    const float hn = (hp - muS[lr]) * rsS[lr] * gv[j] + bv[j];
                    const unsigned short rb = f2bf(hn + acc[i][j][r]);
                    ((unsigned short*)Cv)[(size_t)row * 512 + col] = rb;
                    const float rv = bf2f_u(rb);
                    s1 += rv; s2 += rv * rv;
                }
                #pragma unroll
                for (int m = 1; m < 16; m <<= 1) {
                    s1 += __shfl_xor(s1, m, 64);
                    s2 += __shfl_xor(s2, m, 64);
                }
                if (l15 == 0) {
                    partOut[(size_t)row * 32 + slot * 2 + 0] = s1;
                    partOut[(size_t)row * 32 + slot * 2 + 1] = s2;
                }
            }
    }
}

// ---------------- MFMA flash attention (unchanged from R7) ---------------
__global__ __launch_bounds__(256) void attn_mfma(
    const unsigned short* __restrict__ qk, const unsigned short* __restrict__ vT,
    const float* __restrict__ maskadd, unsigned short* __restrict__ o)
{
    constexpr int PST = 132;
    __shared__ unsigned short Ks[2][128][32];
    __shared__ unsigned short Vs[4][64][32];
    __shared__ unsigned short Ps[4][16][PST];
    __shared__ float Madd[128];
    const int tid = threadIdx.x;
    const int wave = tid >> 6, lane = tid & 63;
    const int b  = blockIdx.x & 7;
    const int hh = (blockIdx.x >> 3) & 7;
    const int qt = blockIdx.x >> 6;
    const int q0 = qt << 7;
    const int l15 = lane & 15, lg = lane >> 4;
    const int srow = lane >> 2;
    const int scol = (lane & 3) << 3;

    #pragma unroll
    for (int t = 0; t < 2; ++t)
        #pragma unroll
        for (int p = 0; p < 2; ++p)
            GLDS16(qk + (size_t)((b << 10) + q0 + (t << 6) + (wave << 4) + srow) * 1024
                      + (hh << 6) + (p << 5) + scol,
                   &Ks[p][(t << 6) + (wave << 4)][0]);
    __syncthreads();
    bf16x8 qf[2][2];
    #pragma unroll
    for (int s = 0; s < 2; ++s)
        #pragma unroll
        for (int p = 0; p < 2; ++p)
            qf[s][p] = *(const bf16x8*)&Ks[p][(s << 6) + (wave << 4) + l15][lg << 3];

    f32x4 oacc[2][4] = {};
    float l_part[2][4] = {};

    for (int kt = 0; kt < 8; ++kt) {
        const int k0 = kt << 7;
        __syncthreads();
        #pragma unroll
        for (int t = 0; t < 2; ++t)
            #pragma unroll
            for (int p = 0; p < 2; ++p)
                GLDS16(qk + (size_t)((b << 10) + k0 + (t << 6) + (wave << 4) + srow) * 1024
                          + 512 + (hh << 6) + (p << 5) + scol,
                       &Ks[p][(t << 6) + (wave << 4)][0]);
        #pragma unroll
        for (int kp = 0; kp < 4; ++kp)
            GLDS16(vT + (size_t)((((b << 3) + hh) << 6) + (wave << 4) + srow) * 1024
                      + k0 + (kp << 5) + scol,
                   &Vs[kp][wave << 4][0]);
        if (tid < 128) Madd[tid] = maskadd[(b << 10) + k0 + tid];
        __syncthreads();

        f32x4 sacc[2][8] = {};
        #pragma unroll
        for (int j = 0; j < 8; ++j) {
            const bf16x8 kf0 = *(const bf16x8*)&Ks[0][(j << 4) + l15][lg << 3];
            const bf16x8 kf1 = *(const bf16x8*)&Ks[1][(j << 4) + l15][lg << 3];
            #pragma unroll
            for (int s = 0; s < 2; ++s) {
                sacc[s][j] = __builtin_amdgcn_mfma_f32_16x16x32_bf16(qf[s][0], kf0, sacc[s][j], 0, 0, 0);
                sacc[s][j] = __builtin_amdgcn_mfma_f32_16x16x32_bf16(qf[s][1], kf1, sacc[s][j], 0, 0, 0);
            }
        }

        bf16x8 vf[4][4];
        #pragma unroll
        for (int kp = 0; kp < 4; ++kp)
            #pragma unroll
            for (int j = 0; j < 4; ++j)
                vf[kp][j] = *(const bf16x8*)&Vs[kp][(j << 4) + l15][lg << 3];

        float ma[8];
        #pragma unroll
        for (int j = 0; j < 8; ++j) ma[j] = Madd[(j << 4) + l15];

        #pragma unroll
        for (int s = 0; s < 2; ++s) {
            #pragma unroll
            for (int j = 0; j < 8; ++j)
                #pragma unroll
                for (int r = 0; r < 4; ++r) {
                    const float p = exp2f(sacc[s][j][r] + ma[j]);
                    l_part[s][r] += p;
                    Ps[wave][(lg << 2) + r][(j << 4) + l15] = f2bf_fast(p);
                }
            __asm__ volatile("s_waitcnt lgkmcnt(0)" ::: "memory");
            #pragma unroll
            for (int kp = 0; kp < 4; ++kp) {
                const bf16x8 pa = *(const bf16x8*)&Ps[wave][l15][(kp << 5) + (lg << 3)];
                #pragma unroll
                for (int j = 0; j < 4; ++j)
                    oacc[s][j] = __builtin_amdgcn_mfma_f32_16x16x32_bf16(pa, vf[kp][j], oacc[s][j], 0, 0, 0);
            }
            __asm__ volatile("s_waitcnt lgkmcnt(0)" ::: "memory");
        }
    }

    #pragma unroll
    for (int s = 0; s < 2; ++s)
        #pragma unroll
        for (int r = 0; r < 4; ++r) {
            float l = l_part[s][r];
            #pragma unroll
            for (int m = 1; m < 16; m <<= 1) l += __shfl_xor(l, m, 64);
            l_part[s][r] = 1.0f / l;
        }
    #pragma unroll
    for (int s = 0; s < 2; ++s) {
        const int tokr = (b << 10) + q0 + (s << 6) + (wave << 4) + (lg << 2);
        #pragma unroll
        for (int j = 0; j < 4; ++j)
            #pragma unroll
            for (int r = 0; r < 4; ++r)
                o[(size_t)(tokr + r) * 512 + (hh << 6) + (j << 4) + l15] =
                    f2bf(oacc[s][j][r] * l_part[s][r]);
    }
}

// ---------------- fused LN2 + final LN + masked mean pool ----------------
__global__ __launch_bounds__(256) void pool_ln(
    const unsigned short* __restrict__ res, const float* __restrict__ stats,
    const float* __restrict__ notpad,
    const float* __restrict__ g2l, const float* __restrict__ b2l,
    const float* __restrict__ gf, const float* __restrict__ bfp,
    float* __restrict__ pooled, float* __restrict__ counts)
{
    __shared__ float sh[512];
    const int b = blockIdx.y, s0 = blockIdx.x << 5;
    const int wave = threadIdx.x >> 6, lane = threadIdx.x & 63;
    const int d0 = lane << 3;
    float g2v[8], b2v[8], gg[8], bb[8];
    ld4(g2v, g2l + d0); ld4(g2v + 4, g2l + d0 + 4);
    ld4(b2v, b2l + d0); ld4(b2v + 4, b2l + d0 + 4);
    ld4(gg, gf + d0); ld4(gg + 4, gf + d0 + 4);
    ld4(bb, bfp + d0); ld4(bb + 4, bfp + d0 + 4);
    float accv[8] = {};
    for (int t = 0; t < 8; ++t) {
        const int tok = (b << 10) + s0 + (wave << 3) + t;
        const float w = notpad[tok];
        // stats of raw res (16 partial slots)
        float s1 = stats[(size_t)tok * 32 + ((lane & 15) << 1)];
        float s2 = stats[(size_t)tok * 32 + ((lane & 15) << 1) + 1];
        #pragma unroll
        for (int m = 1; m < 16; m <<= 1) {
            s1 += __shfl_xor(s1, m, 64);
            s2 += __shfl_xor(s2, m, 64);
        }
        const float mu2 = s1 * (1.0f / Dc);
        const float rs2 = rsqrtf(s2 * (1.0f / Dc) - mu2 * mu2 + 1e-5f);
        const bf16x8 hv = *(const bf16x8*)(res + (size_t)tok * Dc + d0);
        float h2[8], sum = 0.f, sumsq = 0.f;
        #pragma unroll
        for (int j = 0; j < 8; ++j) {
            h2[j] = (bf2f_s(hv[j]) - mu2) * rs2 * g2v[j] + b2v[j];
            sum += h2[j]; sumsq += h2[j] * h2[j];
        }
        #pragma unroll
        for (int m = 1; m < 64; m <<= 1) {
            sum   += __shfl_xor(sum, m, 64);
            sumsq += __shfl_xor(sumsq, m, 64);
        }
        const float mu = sum * (1.0f / Dc);
        const float rstd = rsqrtf(sumsq * (1.0f / Dc) - mu * mu + 1e-5f);
        #pragma unroll
        for (int j = 0; j < 8; ++j)
            accv[j] = fmaf(w, (h2[j] - mu) * rstd * gg[j] + bb[j], accv[j]);
    }
    sh[threadIdx.x] = 0.f; sh[threadIdx.x + 256] = 0.f;
    __syncthreads();
    #pragma unroll
    for (int j = 0; j < 8; ++j) atomicAdd(&sh[d0 + j], accv[j]);
    __syncthreads();
    atomicAdd(&pooled[b * Dc + threadIdx.x], sh[threadIdx.x]);
    atomicAdd(&pooled[b * Dc + 256 + threadIdx.x], sh[threadIdx.x + 256]);
    if (threadIdx.x < 32) {
        float w = notpad[(b << 10) + s0 + threadIdx.x];
        #pragma unroll
        for (int m = 1; m < 32; m <<= 1) w += __shfl_xor(w, m, 64);
        if (threadIdx.x == 0) atomicAdd(&counts[b], w);
    }
}

// ---------------- final tiny GEMV ----------------------------------------
__global__ void out_kernel(
    const float* __restrict__ pooled, const float* __restrict__ counts,
    const float* __restrict__ Wout, const float* __restrict__ bout,
    float* __restrict__ out)
{
    const int bo = blockIdx.x;
    const int b = bo / OUTc, oc = bo % OUTc;
    const int lane = threadIdx.x;
    float acc = 0.f;
    for (int d = lane; d < Dc; d += 64)
        acc = fmaf(pooled[b * Dc + d], Wout[(size_t)d * OUTc + oc], acc);
    #pragma unroll
    for (int m = 1; m < 64; m <<= 1) acc += __shfl_xor(acc, m, 64);
    if (lane == 0) out[b * OUTc + oc] = acc / (counts[b] + 1e-8f) + bout[oc];
}

} // namespace

extern "C" void kernel_launch(void* const* d_in, const int* in_sizes, int n_in,
                              void* d_out, int out_size, void* d_ws, size_t ws_size,
                              hipStream_t stream)
{
    (void)in_sizes; (void)n_in; (void)out_size; (void)ws_size;
    const float* x     = (const float*)d_in[0];
    const float* Wproj = (const float*)d_in[1];
    const float* bproj = (const float*)d_in[2];
    const float* gp    = (const float*)d_in[3];
    const float* bp    = (const float*)d_in[4];
    const float* Wq    = (const float*)d_in[5];
    const float* Wk    = (const float*)d_in[6];
    const float* Wv    = (const float*)d_in[7];
    const float* Wo    = (const float*)d_in[8];
    const float* g1    = (const float*)d_in[9];
    const float* b1    = (const float*)d_in[10];
    const float* W1    = (const float*)d_in[11];
    const float* W2    = (const float*)d_in[12];
    const float* g2    = (const float*)d_in[13];
    const float* b2    = (const float*)d_in[14];
    const float* gf    = (const float*)d_in[15];
    const float* bf    = (const float*)d_in[16];
    const float* Wout  = (const float*)d_in[17];
    const float* bout  = (const float*)d_in[18];
    float* out = (float*)d_out;

    const size_t MiB = 1u << 20;
    char* base = (char*)d_ws;
    unsigned short* res     = (unsigned short*)(base);              // 8 MiB raw stream
    unsigned short* res1    = (unsigned short*)(base + 8 * MiB);    // 8 MiB
    float*          partA   = (float*)(base + 16 * MiB);            // 1 MiB [8192][16][2]
    float*          partB   = (float*)(base + 17 * MiB);            // 1 MiB
    float*          cvec    = (float*)(base + 18 * MiB);            // c1qkv|c2qkv|c1w1|c2w1|pooled|counts
    float*          c1qkv   = cvec;                                 // 4*1536
    float*          c2qkv   = cvec + 6144;
    float*          c1w1    = cvec + 12288;                         // 4*2048
    float*          c2w1    = cvec + 20480;
    float*          pooled  = cvec + 28672;                         // 4096
    float*          counts  = cvec + 32768;                         // 8
    float*          notpad  = (float*)(base + 19 * MiB);
    float*          maskadd = notpad + 8192;
    unsigned short* qk_act  = (unsigned short*)(base + 24 * MiB);   // 16 MiB
    unsigned short* vT      = (unsigned short*)(base + 40 * MiB);   // 8 MiB
    unsigned short* ob_bf   = (unsigned short*)(base + 48 * MiB);   // 8 MiB
    unsigned short* ffa_bf  = (unsigned short*)(base + 24 * MiB);   // 32 MiB (aliases)
    unsigned short* qkvT    = (unsigned short*)(base + 72 * MiB);   // 6 MiB
    unsigned short* WoT     = (unsigned short*)(base + 78 * MiB);   // 2 MiB
    unsigned short* W1T     = (unsigned short*)(base + 80 * MiB);   // 8 MiB
    unsigned short* W2T     = (unsigned short*)(base + 88 * MiB);   // 8 MiB

    const int M = Bc * Sc;   // 8192

    hipMemsetAsync(cvec, 0, (size_t)(32768 + 8) * sizeof(float), stream);
    castAll<<<3072, 256, 0, stream>>>(Wq, Wk, Wv, Wo, W1, W2,
        gp, bp, g1, b1, g2, b2, qkvT, WoT, W1T, W2T, c1qkv, c2qkv, c1w1, c2w1);
    proj_pe<<<M / 4, 256, 0, stream>>>(x, Wproj, bproj, res, partA, notpad, maskadd);

    for (int l = 0; l < Lc; ++l) {
        const int np = (l == 0) ? 1 : 16;
        const float* gprev = (l == 0) ? gp : g2 + (size_t)(l - 1) * 512;
        const float* bprev = (l == 0) ? bp : b2 + (size_t)(l - 1) * 512;
        gemm_bf16<3, 128><<<dim3(QS / 128, M / 128), 256, 0, stream>>>(
            res, qkvT + (size_t)l * QS * 512, qk_act, vT,
            partA, np, c1qkv + (size_t)l * QS, c2qkv + (size_t)l * QS,
            nullptr, nullptr, nullptr, nullptr, M, QS, 512);
        attn_mfma<<<Bc * Hc * (Sc / 128), 256, 0, stream>>>(qk_act, vT, maskadd, ob_bf);
        gemm_bf16<4, 64><<<dim3(512 / 64, M / 128), 256, 0, stream>>>(
            ob_bf, WoT + (size_t)l * 512 * 512, res1, nullptr,
            partA, np, nullptr, nullptr, res, gprev, bprev, partB, M, 512, 512);
        gemm_bf16<1, 128><<<dim3(FFc / 128, M / 128), 256, 0, stream>>>(
            res1, W1T + (size_t)l * FFc * 512, ffa_bf, nullptr,
            partB, 16, c1w1 + (size_t)l * FFc, c2w1 + (size_t)l * FFc,
            nullptr, nullptr, nullptr, nullptr, M, FFc, 512);
        gemm_bf16<5, 64><<<dim3(512 / 64, M / 128), 256, 0, stream>>>(
            ffa_bf, W2T + (size_t)l * 512 * FFc, res, nullptr,
            partB, 16, nullptr, nullptr, res1,
            g1 + (size_t)l * 512, b1 + (size_t)l * 512, partA, M, 512, FFc);
    }

    pool_ln<<<dim3(Sc / 32, Bc), 256, 0, stream>>>(
        res, partA, notpad, g2 + (size_t)3 * 512, b2 + (size_t)3 * 512,
        gf, bf, pooled, counts);
    out_kernel<<<Bc * OUTc, 64, 0, stream>>>(pooled, counts, Wout, bout, out);
}

// Round 9
// 783.192 us; speedup vs baseline: 1.1825x; 1.1825x over previous
//
#include <hip/hip_runtime.h>
#include <math.h>
#include <stdint.h>

namespace {

constexpr int Bc = 8, Sc = 1024, Dc = 512, Hc = 8, FFc = 2048, Lc = 4, OUTc = 6;
constexpr int QS = 1536;   // fused qkv weight col count

typedef __attribute__((ext_vector_type(8))) short  bf16x8;
typedef __attribute__((ext_vector_type(4))) float  f32x4;

__device__ __forceinline__ void ld4(float d[4], const float* s) {
    float4 t = *(const float4*)s;
    d[0] = t.x; d[1] = t.y; d[2] = t.z; d[3] = t.w;
}
__device__ __forceinline__ float bf2f_s(short u) {
    union { uint32_t i; float f; } c; c.i = ((uint32_t)(unsigned short)u) << 16; return c.f;
}
__device__ __forceinline__ unsigned short f2bf(float f) {   // RNE
    union { float f; uint32_t i; } c; c.f = f;
    uint32_t r = c.i + 0x7FFF + ((c.i >> 16) & 1);
    return (unsigned short)(r >> 16);
}
__device__ __forceinline__ unsigned short f2bf_fast(float f) {  // round-half-up
    union { float f; uint32_t i; } c; c.f = f;
    return (unsigned short)((c.i + 0x8000u) >> 16);
}

#define GLDS16(gp, lp) __builtin_amdgcn_global_load_lds(                      \
    (const __attribute__((address_space(1))) uint32_t*)(gp),                  \
    (__attribute__((address_space(3))) uint32_t*)(lp), 16, 0, 0)

// ---------------- all weight transposes+casts in ONE dispatch ------------
__global__ __launch_bounds__(256) void castAll(
    const float* __restrict__ Wq, const float* __restrict__ Wk,
    const float* __restrict__ Wv, const float* __restrict__ Wo,
    const float* __restrict__ W1, const float* __restrict__ W2,
    unsigned short* __restrict__ qkvT, unsigned short* __restrict__ WoT,
    unsigned short* __restrict__ W1T, unsigned short* __restrict__ W2T)
{
    const int t = blockIdx.x;
    const float* in; unsigned short* out; int K, N, k0, n0;
    if (t < 1024) {            // qkvo: 16 mats x 8x8 tiles of 512x512
        const int mat = t >> 6, l = mat >> 2, w = mat & 3;
        K = 512; N = 512;
        k0 = ((t >> 3) & 7) << 6; n0 = (t & 7) << 6;
        const float* ws4[4] = {Wq, Wk, Wv, Wo};
        in = ws4[w] + (size_t)l * 512 * 512;
        out = (w < 3) ? qkvT + (size_t)l * QS * 512 + (size_t)w * 512 * 512
                      : WoT + (size_t)l * 512 * 512;
    } else if (t < 2048) {     // W1
        const int u = t - 1024, l = u >> 8;
        K = 512; N = 2048;
        k0 = ((u >> 5) & 7) << 6; n0 = (u & 31) << 6;
        in = W1 + (size_t)l * 512 * 2048;
        out = W1T + (size_t)l * 2048 * 512;
    } else {                   // W2
        const int u = t - 2048, l = u >> 8;
        K = 2048; N = 512;
        k0 = ((u >> 3) & 31) << 6; n0 = (u & 7) << 6;
        in = W2 + (size_t)l * 2048 * 512;
        out = W2T + (size_t)l * 512 * 2048;
    }
    __shared__ float tbuf[64][65];
    const int c = threadIdx.x & 63, r4 = threadIdx.x >> 6;
    #pragma unroll
    for (int it = 0; it < 16; ++it) {
        const int r = (it << 2) + r4;
        tbuf[r][c] = in[(size_t)(k0 + r) * N + n0 + c];
    }
    __syncthreads();
    #pragma unroll
    for (int it = 0; it < 16; ++it) {
        const int r = (it << 2) + r4;
        out[(size_t)(n0 + r) * K + k0 + c] = f2bf(tbuf[c][r]);
    }
}

// ---------------- proj + positional encoding + layernorm (bf16 out) ------
__global__ __launch_bounds__(256) void proj_pe_ln(
    const float* __restrict__ x, const float* __restrict__ Wproj,
    const float* __restrict__ bproj, const float* __restrict__ gp,
    const float* __restrict__ bp, unsigned short* __restrict__ hbf,
    float* __restrict__ notpad, float* __restrict__ maskadd)
{
    const int wave = threadIdx.x >> 6, lane = threadIdx.x & 63;
    const int tok = (blockIdx.x << 2) + wave;
    const int s = tok & (Sc - 1);
    const float x0 = x[tok * 3 + 0], x1 = x[tok * 3 + 1], x2 = x[tok * 3 + 2];
    if (lane == 0) {
        const bool pad = (fabsf(x0) + fabsf(x1) + fabsf(x2) == 0.0f);
        notpad[tok]  = pad ? 0.0f : 1.0f;
        maskadd[tok] = pad ? -1e30f : 0.0f;
    }
    const float c = -logf(10000.0f) / (float)Dc;
    float v[8];
    float sum = 0.f, sumsq = 0.f;
    const int d0 = lane << 3;
    #pragma unroll
    for (int j = 0; j < 8; ++j) {
        const int d = d0 + j;
        float val = fmaf(x0, Wproj[d],
                    fmaf(x1, Wproj[Dc + d],
                    fmaf(x2, Wproj[2 * Dc + d], bproj[d])));
        const float arg = (float)s * expf((float)(d & ~1) * c);
        val += (d & 1) ? cosf(arg) : sinf(arg);
        v[j] = val;
        sum += val; sumsq += val * val;
    }
    #pragma unroll
    for (int m = 1; m < 64; m <<= 1) {
        sum   += __shfl_xor(sum, m, 64);
        sumsq += __shfl_xor(sumsq, m, 64);
    }
    const float mu = sum * (1.0f / Dc);
    const float rstd = rsqrtf(sumsq * (1.0f / Dc) - mu * mu + 1e-5f);
    float gg[8], bb[8];
    ld4(gg, gp + d0); ld4(gg + 4, gp + d0 + 4);
    ld4(bb, bp + d0); ld4(bb + 4, bp + d0 + 4);
    bf16x8 rb;
    #pragma unroll
    for (int j = 0; j < 8; ++j)
        rb[j] = (short)f2bf((v[j] - mu) * rstd * gg[j] + bb[j]);
    *(bf16x8*)(hbf + (size_t)tok * Dc + d0) = rb;
}

// ---------------- residual add + layernorm, all bf16 ---------------------
__global__ __launch_bounds__(256) void add_ln(
    const unsigned short* __restrict__ hin, const unsigned short* __restrict__ delta,
    const float* __restrict__ g, const float* __restrict__ b,
    unsigned short* __restrict__ hout)
{
    const int wave = threadIdx.x >> 6, lane = threadIdx.x & 63;
    const int tok = (blockIdx.x << 2) + wave;
    const int d0 = lane << 3;
    const size_t base = (size_t)tok * Dc + d0;
    const bf16x8 hv = *(const bf16x8*)(hin + base);
    const bf16x8 dv = *(const bf16x8*)(delta + base);
    float v[8];
    float sum = 0.f, sumsq = 0.f;
    #pragma unroll
    for (int j = 0; j < 8; ++j) {
        v[j] = bf2f_s(hv[j]) + bf2f_s(dv[j]);
        sum += v[j]; sumsq += v[j] * v[j];
    }
    #pragma unroll
    for (int m = 1; m < 64; m <<= 1) {
        sum   += __shfl_xor(sum, m, 64);
        sumsq += __shfl_xor(sumsq, m, 64);
    }
    const float mu = sum * (1.0f / Dc);
    const float rstd = rsqrtf(sumsq * (1.0f / Dc) - mu * mu + 1e-5f);
    float gg[8], bb[8];
    ld4(gg, g + d0); ld4(gg + 4, g + d0 + 4);
    ld4(bb, b + d0); ld4(bb + 4, b + d0 + 4);
    bf16x8 rb;
    #pragma unroll
    for (int j = 0; j < 8; ++j)
        rb[j] = (short)f2bf((v[j] - mu) * rstd * gg[j] + bb[j]);
    *(bf16x8*)(hout + base) = rb;
}

// ---------------- bf16 MFMA GEMM: C[M,N] = epi(A[M,K] @ Bt[N,K]^T) -------
// 128xNT tile, BK=64, XOR-swizzled LDS (global-side), direct C stores.
// 1-D grid, XCD-aware decode: mtile = bid % 64, ntile = bid / 64 so all
// N-tiles of one M-tile share an XCD (A-tile fetched once into that L2).
// EPI: 1 = silu + bf16, 2 = bf16,
//      3 = qkv: n<512 -> q*(0.125*log2e) (stride 1024); 512..1023 -> k;
//               n>=1024 -> v transposed via LDS to vT[bh][dh][s]
template<int EPI, int NT>
__global__ __launch_bounds__(256) void gemm_bf16(
    const unsigned short* __restrict__ A, const unsigned short* __restrict__ Bt,
    void* __restrict__ Cv, void* __restrict__ Cv2, int M, int N, int K)
{
    constexpr int JN = NT / 32;
    constexpr int TR = 140;                     // vT repack row stride
    constexpr int ABsz = 128 * 64 + NT * 64;    // shorts
    constexpr int SMsz = (EPI == 3 && 128 * TR > ABsz) ? 128 * TR : ABsz;
    __shared__ unsigned short smem[SMsz];
    unsigned short* As = smem;
    unsigned short* Bs = smem + 128 * 64;
    const int tid = threadIdx.x;
    const int wave = tid >> 6, lane = tid & 63;
    const int mtiles = M >> 7;                  // 64 (multiple of 8)
    const int m0 = (blockIdx.x % mtiles) << 7;
    const int n0 = (blockIdx.x / mtiles) * NT;
    const int wm = (wave >> 1) << 6;
    const int wn = (wave & 1) * (NT / 2);
    const int l15 = lane & 15;
    const int lg  = lane >> 4;
    const int grow  = lane >> 3;
    const int gcolk = ((lane & 7) ^ grow) << 3;

    f32x4 acc[4][JN] = {};

    for (int k0 = 0; k0 < K; k0 += 64) {
        __syncthreads();
        #pragma unroll
        for (int t = 0; t < 4; ++t) {
            const int rb = (t << 5) + (wave << 3);
            GLDS16(A + (size_t)(m0 + rb + grow) * K + k0 + gcolk, &As[rb * 64]);
        }
        #pragma unroll
        for (int t = 0; t < NT / 32; ++t) {
            const int rb = (t << 5) + (wave << 3);
            GLDS16(Bt + (size_t)(n0 + rb + grow) * K + k0 + gcolk, &Bs[rb * 64]);
        }
        __syncthreads();
        #pragma unroll
        for (int h = 0; h < 2; ++h) {
            const int sw = (((h << 2) + lg) ^ (l15 & 7)) << 3;
            bf16x8 af[4], bfr[JN];
            #pragma unroll
            for (int i = 0; i < 4; ++i)
                af[i] = *(const bf16x8*)&As[(wm + (i << 4) + l15) * 64 + sw];
            #pragma unroll
            for (int j = 0; j < JN; ++j)
                bfr[j] = *(const bf16x8*)&Bs[(wn + (j << 4) + l15) * 64 + sw];
            #pragma unroll
            for (int i = 0; i < 4; ++i)
                #pragma unroll
                for (int j = 0; j < JN; ++j)
                    acc[i][j] = __builtin_amdgcn_mfma_f32_16x16x32_bf16(
                        af[i], bfr[j], acc[i][j], 0, 0, 0);
        }
    }

    if constexpr (EPI == 3) {
        if (n0 >= 1024) {          // V: transpose [n][m] via LDS, b128 writes
            __syncthreads();
            unsigned short* Tr = smem;
            #pragma unroll
            for (int i = 0; i < 4; ++i)
                #pragma unroll
                for (int j = 0; j < JN; ++j)
                    #pragma unroll
                    for (int r = 0; r < 4; ++r)
                        Tr[(wn + (j << 4) + l15) * TR + wm + (i << 4) + (lg << 2) + r]
                            = f2bf(acc[i][j][r]);
            __syncthreads();
            const int bb = m0 >> 10, s0 = m0 & 1023;
            #pragma unroll
            for (int it = 0; it < 8; ++it) {
                const int idx = (it << 8) + tid;
                const int ln = idx >> 4, lmc = (idx & 15) << 3;
                const int gcol = n0 - 1024 + ln;
                const int head = gcol >> 6, dh = gcol & 63;
                *(bf16x8*)((unsigned short*)Cv2 +
                    (size_t)((((bb << 3) + head) << 6) + dh) * 1024 + s0 + lmc) =
                    *(const bf16x8*)&Tr[ln * TR + lmc];
            }
            return;
        }
    }

    const float qsc = 0.125f * 1.44269504f;   // fold 1/sqrt(DH)*log2(e) into q
    const int crow0 = m0 + wm + (lg << 2);
    const int ccol0 = n0 + wn + l15;
    #pragma unroll
    for (int i = 0; i < 4; ++i)
        #pragma unroll
        for (int j = 0; j < JN; ++j)
            #pragma unroll
            for (int r = 0; r < 4; ++r) {
                const int row = crow0 + (i << 4) + r;
                const int col = ccol0 + (j << 4);
                float v = acc[i][j][r];
                if (EPI == 3) {
                    if (n0 < 512) v *= qsc;
                    ((unsigned short*)Cv)[(size_t)row * 1024 + col] = f2bf(v);
                } else {
                    if (EPI == 1) v = v / (1.0f + expf(-v));
                    ((unsigned short*)Cv)[(size_t)row * N + col] = f2bf(v);
                }
            }
}

// ---------------- MFMA flash attention, DH=64, 128-q blocks --------------
__global__ __launch_bounds__(256) void attn_mfma(
    const unsigned short* __restrict__ qk,   // [8192][1024] bf16, q' | k
    const unsigned short* __restrict__ vT,   // [64 bh][64 dh][1024 s] bf16
    const float* __restrict__ maskadd,       // 0 or -1e30 per token
    unsigned short* __restrict__ o)          // [8192][512] bf16
{
    constexpr int PST = 132;
    __shared__ unsigned short Ks[2][128][32];
    __shared__ unsigned short Vs[4][64][32];
    __shared__ unsigned short Ps[4][16][PST];
    __shared__ float Madd[128];
    const int tid = threadIdx.x;
    const int wave = tid >> 6, lane = tid & 63;
    const int b  = blockIdx.x & 7;
    const int hh = (blockIdx.x >> 3) & 7;
    const int qt = blockIdx.x >> 6;
    const int q0 = qt << 7;
    const int l15 = lane & 15, lg = lane >> 4;
    const int srow = lane >> 2;
    const int scol = (lane & 3) << 3;

    #pragma unroll
    for (int t = 0; t < 2; ++t)
        #pragma unroll
        for (int p = 0; p < 2; ++p)
            GLDS16(qk + (size_t)((b << 10) + q0 + (t << 6) + (wave << 4) + srow) * 1024
                      + (hh << 6) + (p << 5) + scol,
                   &Ks[p][(t << 6) + (wave << 4)][0]);
    __syncthreads();
    bf16x8 qf[2][2];
    #pragma unroll
    for (int s = 0; s < 2; ++s)
        #pragma unroll
        for (int p = 0; p < 2; ++p)
            qf[s][p] = *(const bf16x8*)&Ks[p][(s << 6) + (wave << 4) + l15][lg << 3];

    f32x4 oacc[2][4] = {};
    float l_part[2][4] = {};

    for (int kt = 0; kt < 8; ++kt) {
        const int k0 = kt << 7;
        __syncthreads();
        #pragma unroll
        for (int t = 0; t < 2; ++t)
            #pragma unroll
            for (int p = 0; p < 2; ++p)
                GLDS16(qk + (size_t)((b << 10) + k0 + (t << 6) + (wave << 4) + srow) * 1024
                          + 512 + (hh << 6) + (p << 5) + scol,
                       &Ks[p][(t << 6) + (wave << 4)][0]);
        #pragma unroll
        for (int kp = 0; kp < 4; ++kp)
            GLDS16(vT + (size_t)((((b << 3) + hh) << 6) + (wave << 4) + srow) * 1024
                      + k0 + (kp << 5) + scol,
                   &Vs[kp][wave << 4][0]);
        if (tid < 128) Madd[tid] = maskadd[(b << 10) + k0 + tid];
        __syncthreads();

        f32x4 sacc[2][8] = {};
        #pragma unroll
        for (int j = 0; j < 8; ++j) {
            const bf16x8 kf0 = *(const bf16x8*)&Ks[0][(j << 4) + l15][lg << 3];
            const bf16x8 kf1 = *(const bf16x8*)&Ks[1][(j << 4) + l15][lg << 3];
            #pragma unroll
            for (int s = 0; s < 2; ++s) {
                sacc[s][j] = __builtin_amdgcn_mfma_f32_16x16x32_bf16(qf[s][0], kf0, sacc[s][j], 0, 0, 0);
                sacc[s][j] = __builtin_amdgcn_mfma_f32_16x16x32_bf16(qf[s][1], kf1, sacc[s][j], 0, 0, 0);
            }
        }

        bf16x8 vf[4][4];
        #pragma unroll
        for (int kp = 0; kp < 4; ++kp)
            #pragma unroll
            for (int j = 0; j < 4; ++j)
                vf[kp][j] = *(const bf16x8*)&Vs[kp][(j << 4) + l15][lg << 3];

        float ma[8];
        #pragma unroll
        for (int j = 0; j < 8; ++j) ma[j] = Madd[(j << 4) + l15];

        #pragma unroll
        for (int s = 0; s < 2; ++s) {
            #pragma unroll
            for (int j = 0; j < 8; ++j)
                #pragma unroll
                for (int r = 0; r < 4; ++r) {
                    const float p = exp2f(sacc[s][j][r] + ma[j]);
                    l_part[s][r] += p;
                    Ps[wave][(lg << 2) + r][(j << 4) + l15] = f2bf_fast(p);
                }
            __asm__ volatile("s_waitcnt lgkmcnt(0)" ::: "memory");
            #pragma unroll
            for (int kp = 0; kp < 4; ++kp) {
                const bf16x8 pa = *(const bf16x8*)&Ps[wave][l15][(kp << 5) + (lg << 3)];
                #pragma unroll
                for (int j = 0; j < 4; ++j)
                    oacc[s][j] = __builtin_amdgcn_mfma_f32_16x16x32_bf16(pa, vf[kp][j], oacc[s][j], 0, 0, 0);
            }
            __asm__ volatile("s_waitcnt lgkmcnt(0)" ::: "memory");  // pa reads done before s=1 overwrites
        }
    }

    #pragma unroll
    for (int s = 0; s < 2; ++s)
        #pragma unroll
        for (int r = 0; r < 4; ++r) {
            float l = l_part[s][r];
            #pragma unroll
            for (int m = 1; m < 16; m <<= 1) l += __shfl_xor(l, m, 64);
            l_part[s][r] = 1.0f / l;
        }
    #pragma unroll
    for (int s = 0; s < 2; ++s) {
        const int tokr = (b << 10) + q0 + (s << 6) + (wave << 4) + (lg << 2);
        #pragma unroll
        for (int j = 0; j < 4; ++j)
            #pragma unroll
            for (int r = 0; r < 4; ++r)
                o[(size_t)(tokr + r) * 512 + (hh << 6) + (j << 4) + l15] =
                    f2bf(oacc[s][j][r] * l_part[s][r]);
    }
}

// ---------------- fused final layernorm + masked mean pool ----------------
__global__ __launch_bounds__(256) void pool_ln(
    const unsigned short* __restrict__ hbf, const float* __restrict__ notpad,
    const float* __restrict__ gf, const float* __restrict__ bfp,
    float* __restrict__ pooled, float* __restrict__ counts)
{
    __shared__ float sh[512];
    const int b = blockIdx.y, s0 = blockIdx.x << 5;
    const int wave = threadIdx.x >> 6, lane = threadIdx.x & 63;
    const int d0 = lane << 3;
    float gg[8], bb[8];
    ld4(gg, gf + d0); ld4(gg + 4, gf + d0 + 4);
    ld4(bb, bfp + d0); ld4(bb + 4, bfp + d0 + 4);
    float accv[8] = {};
    for (int t = 0; t < 8; ++t) {
        const int tok = (b << 10) + s0 + (wave << 3) + t;
        const float w = notpad[tok];
        const bf16x8 hv = *(const bf16x8*)(hbf + (size_t)tok * Dc + d0);
        float v[8], sum = 0.f, sumsq = 0.f;
        #pragma unroll
        for (int j = 0; j < 8; ++j) {
            v[j] = bf2f_s(hv[j]); sum += v[j]; sumsq += v[j] * v[j];
        }
        #pragma unroll
        for (int m = 1; m < 64; m <<= 1) {
            sum   += __shfl_xor(sum, m, 64);
            sumsq += __shfl_xor(sumsq, m, 64);
        }
        const float mu = sum * (1.0f / Dc);
        const float rstd = rsqrtf(sumsq * (1.0f / Dc) - mu * mu + 1e-5f);
        #pragma unroll
        for (int j = 0; j < 8; ++j)
            accv[j] = fmaf(w, (v[j] - mu) * rstd * gg[j] + bb[j], accv[j]);
    }
    sh[threadIdx.x] = 0.f; sh[threadIdx.x + 256] = 0.f;
    __syncthreads();
    #pragma unroll
    for (int j = 0; j < 8; ++j) atomicAdd(&sh[d0 + j], accv[j]);
    __syncthreads();
    atomicAdd(&pooled[b * Dc + threadIdx.x], sh[threadIdx.x]);
    atomicAdd(&pooled[b * Dc + 256 + threadIdx.x], sh[threadIdx.x + 256]);
    if (threadIdx.x < 32) {
        float w = notpad[(b << 10) + s0 + threadIdx.x];
        #pragma unroll
        for (int m = 1; m < 32; m <<= 1) w += __shfl_xor(w, m, 64);
        if (threadIdx.x == 0) atomicAdd(&counts[b], w);
    }
}

// ---------------- final tiny GEMV ----------------------------------------
__global__ void out_kernel(
    const float* __restrict__ pooled, const float* __restrict__ counts,
    const float* __restrict__ Wout, const float* __restrict__ bout,
    float* __restrict__ out)
{
    const int bo = blockIdx.x;
    const int b = bo / OUTc, oc = bo % OUTc;
    const int lane = threadIdx.x;
    float acc = 0.f;
    for (int d = lane; d < Dc; d += 64)
        acc = fmaf(pooled[b * Dc + d], Wout[(size_t)d * OUTc + oc], acc);
    #pragma unroll
    for (int m = 1; m < 64; m <<= 1) acc += __shfl_xor(acc, m, 64);
    if (lane == 0) out[b * OUTc + oc] = acc / (counts[b] + 1e-8f) + bout[oc];
}

} // namespace

extern "C" void kernel_launch(void* const* d_in, const int* in_sizes, int n_in,
                              void* d_out, int out_size, void* d_ws, size_t ws_size,
                              hipStream_t stream)
{
    (void)in_sizes; (void)n_in; (void)out_size; (void)ws_size;
    const float* x     = (const float*)d_in[0];
    const float* Wproj = (const float*)d_in[1];
    const float* bproj = (const float*)d_in[2];
    const float* gp    = (const float*)d_in[3];
    const float* bp    = (const float*)d_in[4];
    const float* Wq    = (const float*)d_in[5];
    const float* Wk    = (const float*)d_in[6];
    const float* Wv    = (const float*)d_in[7];
    const float* Wo    = (const float*)d_in[8];
    const float* g1    = (const float*)d_in[9];
    const float* b1    = (const float*)d_in[10];
    const float* W1    = (const float*)d_in[11];
    const float* W2    = (const float*)d_in[12];
    const float* g2    = (const float*)d_in[13];
    const float* b2    = (const float*)d_in[14];
    const float* gf    = (const float*)d_in[15];
    const float* bf    = (const float*)d_in[16];
    const float* Wout  = (const float*)d_in[17];
    const float* bout  = (const float*)d_in[18];
    float* out = (float*)d_out;

    const size_t MiB = 1u << 20;
    char* base = (char*)d_ws;
    unsigned short* h_bf    = (unsigned short*)(base);              // 8 MiB
    unsigned short* qk_act  = (unsigned short*)(base + 24 * MiB);   // 16 MiB [8192][1024]
    unsigned short* vT      = (unsigned short*)(base + 40 * MiB);   // 8 MiB [64][64][1024]
    unsigned short* ob_bf   = (unsigned short*)(base + 48 * MiB);   // 8 MiB [8192][512]
    unsigned short* bufB_bf = (unsigned short*)(base + 56 * MiB);   // 8 MiB [8192][512]
    unsigned short* ffa_bf  = (unsigned short*)(base + 24 * MiB);   // 32 MiB (aliases qk/vT/ob)
    unsigned short* qkvT    = (unsigned short*)(base + 72 * MiB);   // 6 MiB
    unsigned short* WoT     = (unsigned short*)(base + 78 * MiB);   // 2 MiB
    unsigned short* W1T     = (unsigned short*)(base + 80 * MiB);   // 8 MiB
    unsigned short* W2T     = (unsigned short*)(base + 88 * MiB);   // 8 MiB
    float*          notpad  = (float*)(base + 96 * MiB);            // 32 KiB
    float*          maskadd = notpad + 8192;                        // 32 KiB
    float*          pooled  = maskadd + 8192;
    float*          counts  = pooled + Bc * Dc;

    const int M = Bc * Sc;       // 8192
    const int MT = M / 128;      // 64 m-tiles (multiple of 8 -> XCD swizzle valid)

    castAll<<<3072, 256, 0, stream>>>(Wq, Wk, Wv, Wo, W1, W2, qkvT, WoT, W1T, W2T);
    proj_pe_ln<<<M / 4, 256, 0, stream>>>(x, Wproj, bproj, gp, bp, h_bf, notpad, maskadd);

    for (int l = 0; l < Lc; ++l) {
        gemm_bf16<3, 128><<<(QS / 128) * MT, 256, 0, stream>>>(
            h_bf, qkvT + (size_t)l * QS * 512, qk_act, vT, M, QS, 512);
        attn_mfma<<<Bc * Hc * (Sc / 128), 256, 0, stream>>>(qk_act, vT, maskadd, ob_bf);
        gemm_bf16<2, 64><<<(512 / 64) * MT, 256, 0, stream>>>(
            ob_bf, WoT + (size_t)l * 512 * 512, bufB_bf, nullptr, M, 512, 512);
        add_ln<<<M / 4, 256, 0, stream>>>(h_bf, bufB_bf, g1 + (size_t)l * Dc, b1 + (size_t)l * Dc, h_bf);
        gemm_bf16<1, 128><<<(FFc / 128) * MT, 256, 0, stream>>>(
            h_bf, W1T + (size_t)l * FFc * 512, ffa_bf, nullptr, M, FFc, 512);
        gemm_bf16<2, 64><<<(512 / 64) * MT, 256, 0, stream>>>(
            ffa_bf, W2T + (size_t)l * 512 * FFc, bufB_bf, nullptr, M, 512, FFc);
        add_ln<<<M / 4, 256, 0, stream>>>(h_bf, bufB_bf, g2 + (size_t)l * Dc, b2 + (size_t)l * Dc, h_bf);
    }

    hipMemsetAsync(pooled, 0, (size_t)(Bc * Dc + Bc) * sizeof(float), stream);
    pool_ln<<<dim3(Sc / 32, Bc), 256, 0, stream>>>(h_bf, notpad, gf, bf, pooled, counts);
    out_kernel<<<Bc * OUTc, 64, 0, stream>>>(pooled, counts, Wout, bout, out);
}

// Round 10
// 766.603 us; speedup vs baseline: 1.2081x; 1.0216x over previous
//
#include <hip/hip_runtime.h>
#include <math.h>
#include <stdint.h>

namespace {

constexpr int Bc = 8, Sc = 1024, Dc = 512, Hc = 8, FFc = 2048, Lc = 4, OUTc = 6;
constexpr int QS = 1536;   // fused qkv weight col count

typedef __attribute__((ext_vector_type(8))) short  bf16x8;
typedef __attribute__((ext_vector_type(4))) float  f32x4;

__device__ __forceinline__ void ld4(float d[4], const float* s) {
    float4 t = *(const float4*)s;
    d[0] = t.x; d[1] = t.y; d[2] = t.z; d[3] = t.w;
}
__device__ __forceinline__ float bf2f_s(short u) {
    union { uint32_t i; float f; } c; c.i = ((uint32_t)(unsigned short)u) << 16; return c.f;
}
__device__ __forceinline__ unsigned short f2bf(float f) {   // RNE
    union { float f; uint32_t i; } c; c.f = f;
    uint32_t r = c.i + 0x7FFF + ((c.i >> 16) & 1);
    return (unsigned short)(r >> 16);
}
__device__ __forceinline__ unsigned short f2bf_fast(float f) {  // round-half-up
    union { float f; uint32_t i; } c; c.f = f;
    return (unsigned short)((c.i + 0x8000u) >> 16);
}

#define GLDS16(gp, lp) __builtin_amdgcn_global_load_lds(                      \
    (const __attribute__((address_space(1))) uint32_t*)(gp),                  \
    (__attribute__((address_space(3))) uint32_t*)(lp), 16, 0, 0)

// ---------------- all weight transposes+casts in ONE dispatch ------------
__global__ __launch_bounds__(256) void castAll(
    const float* __restrict__ Wq, const float* __restrict__ Wk,
    const float* __restrict__ Wv, const float* __restrict__ Wo,
    const float* __restrict__ W1, const float* __restrict__ W2,
    unsigned short* __restrict__ qkvT, unsigned short* __restrict__ WoT,
    unsigned short* __restrict__ W1T, unsigned short* __restrict__ W2T)
{
    const int t = blockIdx.x;
    const float* in; unsigned short* out; int K, N, k0, n0;
    if (t < 1024) {            // qkvo: 16 mats x 8x8 tiles of 512x512
        const int mat = t >> 6, l = mat >> 2, w = mat & 3;
        K = 512; N = 512;
        k0 = ((t >> 3) & 7) << 6; n0 = (t & 7) << 6;
        const float* ws4[4] = {Wq, Wk, Wv, Wo};
        in = ws4[w] + (size_t)l * 512 * 512;
        out = (w < 3) ? qkvT + (size_t)l * QS * 512 + (size_t)w * 512 * 512
                      : WoT + (size_t)l * 512 * 512;
    } else if (t < 2048) {     // W1
        const int u = t - 1024, l = u >> 8;
        K = 512; N = 2048;
        k0 = ((u >> 5) & 7) << 6; n0 = (u & 31) << 6;
        in = W1 + (size_t)l * 512 * 2048;
        out = W1T + (size_t)l * 2048 * 512;
    } else {                   // W2
        const int u = t - 2048, l = u >> 8;
        K = 2048; N = 512;
        k0 = ((u >> 3) & 31) << 6; n0 = (u & 7) << 6;
        in = W2 + (size_t)l * 2048 * 512;
        out = W2T + (size_t)l * 512 * 2048;
    }
    __shared__ float tbuf[64][65];
    const int c = threadIdx.x & 63, r4 = threadIdx.x >> 6;
    #pragma unroll
    for (int it = 0; it < 16; ++it) {
        const int r = (it << 2) + r4;
        tbuf[r][c] = in[(size_t)(k0 + r) * N + n0 + c];
    }
    __syncthreads();
    #pragma unroll
    for (int it = 0; it < 16; ++it) {
        const int r = (it << 2) + r4;
        out[(size_t)(n0 + r) * K + k0 + c] = f2bf(tbuf[c][r]);
    }
}

// ---------------- proj + positional encoding + layernorm (bf16 out) ------
__global__ __launch_bounds__(256) void proj_pe_ln(
    const float* __restrict__ x, const float* __restrict__ Wproj,
    const float* __restrict__ bproj, const float* __restrict__ gp,
    const float* __restrict__ bp, unsigned short* __restrict__ hbf,
    float* __restrict__ notpad, float* __restrict__ maskadd)
{
    const int wave = threadIdx.x >> 6, lane = threadIdx.x & 63;
    const int tok = (blockIdx.x << 2) + wave;
    const int s = tok & (Sc - 1);
    const float x0 = x[tok * 3 + 0], x1 = x[tok * 3 + 1], x2 = x[tok * 3 + 2];
    if (lane == 0) {
        const bool pad = (fabsf(x0) + fabsf(x1) + fabsf(x2) == 0.0f);
        notpad[tok]  = pad ? 0.0f : 1.0f;
        maskadd[tok] = pad ? -1e30f : 0.0f;
    }
    const float c = -logf(10000.0f) / (float)Dc;
    float v[8];
    float sum = 0.f, sumsq = 0.f;
    const int d0 = lane << 3;
    #pragma unroll
    for (int j = 0; j < 8; ++j) {
        const int d = d0 + j;
        float val = fmaf(x0, Wproj[d],
                    fmaf(x1, Wproj[Dc + d],
                    fmaf(x2, Wproj[2 * Dc + d], bproj[d])));
        const float arg = (float)s * expf((float)(d & ~1) * c);
        val += (d & 1) ? cosf(arg) : sinf(arg);
        v[j] = val;
        sum += val; sumsq += val * val;
    }
    #pragma unroll
    for (int m = 1; m < 64; m <<= 1) {
        sum   += __shfl_xor(sum, m, 64);
        sumsq += __shfl_xor(sumsq, m, 64);
    }
    const float mu = sum * (1.0f / Dc);
    const float rstd = rsqrtf(sumsq * (1.0f / Dc) - mu * mu + 1e-5f);
    float gg[8], bb[8];
    ld4(gg, gp + d0); ld4(gg + 4, gp + d0 + 4);
    ld4(bb, bp + d0); ld4(bb + 4, bp + d0 + 4);
    bf16x8 rb;
    #pragma unroll
    for (int j = 0; j < 8; ++j)
        rb[j] = (short)f2bf((v[j] - mu) * rstd * gg[j] + bb[j]);
    *(bf16x8*)(hbf + (size_t)tok * Dc + d0) = rb;
}

// ---------------- residual add + layernorm, all bf16 ---------------------
__global__ __launch_bounds__(256) void add_ln(
    const unsigned short* __restrict__ hin, const unsigned short* __restrict__ delta,
    const float* __restrict__ g, const float* __restrict__ b,
    unsigned short* __restrict__ hout)
{
    const int wave = threadIdx.x >> 6, lane = threadIdx.x & 63;
    const int tok = (blockIdx.x << 2) + wave;
    const int d0 = lane << 3;
    const size_t base = (size_t)tok * Dc + d0;
    const bf16x8 hv = *(const bf16x8*)(hin + base);
    const bf16x8 dv = *(const bf16x8*)(delta + base);
    float v[8];
    float sum = 0.f, sumsq = 0.f;
    #pragma unroll
    for (int j = 0; j < 8; ++j) {
        v[j] = bf2f_s(hv[j]) + bf2f_s(dv[j]);
        sum += v[j]; sumsq += v[j] * v[j];
    }
    #pragma unroll
    for (int m = 1; m < 64; m <<= 1) {
        sum   += __shfl_xor(sum, m, 64);
        sumsq += __shfl_xor(sumsq, m, 64);
    }
    const float mu = sum * (1.0f / Dc);
    const float rstd = rsqrtf(sumsq * (1.0f / Dc) - mu * mu + 1e-5f);
    float gg[8], bb[8];
    ld4(gg, g + d0); ld4(gg + 4, g + d0 + 4);
    ld4(bb, b + d0); ld4(bb + 4, b + d0 + 4);
    bf16x8 rb;
    #pragma unroll
    for (int j = 0; j < 8; ++j)
        rb[j] = (short)f2bf((v[j] - mu) * rstd * gg[j] + bb[j]);
    *(bf16x8*)(hout + base) = rb;
}

// ---------------- bf16 MFMA GEMM: C[M,N] = epi(A[M,K] @ Bt[N,K]^T) -------
// 128xNT tile, BK=64, XOR-swizzled LDS (global-side), direct C stores.
// 1-D grid, XCD-aware decode: mtile = bid % 64, ntile = bid / 64 so all
// N-tiles of one M-tile share an XCD (A-tile fetched once into that L2).
// EPI: 1 = silu + bf16, 2 = bf16,
//      3 = qkv: n<512 -> q*(0.125*log2e) (stride 1024); 512..1023 -> k;
//               n>=1024 -> v transposed via LDS to vT[bh][dh][s]
template<int EPI, int NT>
__global__ __launch_bounds__(256) void gemm_bf16(
    const unsigned short* __restrict__ A, const unsigned short* __restrict__ Bt,
    void* __restrict__ Cv, void* __restrict__ Cv2, int M, int N, int K)
{
    constexpr int JN = NT / 32;
    constexpr int TR = 140;                     // vT repack row stride
    constexpr int ABsz = 128 * 64 + NT * 64;    // shorts
    constexpr int SMsz = (EPI == 3 && 128 * TR > ABsz) ? 128 * TR : ABsz;
    __shared__ unsigned short smem[SMsz];
    unsigned short* As = smem;
    unsigned short* Bs = smem + 128 * 64;
    const int tid = threadIdx.x;
    const int wave = tid >> 6, lane = tid & 63;
    const int mtiles = M >> 7;                  // 64 (multiple of 8)
    const int m0 = (blockIdx.x % mtiles) << 7;
    const int n0 = (blockIdx.x / mtiles) * NT;
    const int wm = (wave >> 1) << 6;
    const int wn = (wave & 1) * (NT / 2);
    const int l15 = lane & 15;
    const int lg  = lane >> 4;
    const int grow  = lane >> 3;
    const int gcolk = ((lane & 7) ^ grow) << 3;

    f32x4 acc[4][JN] = {};

    for (int k0 = 0; k0 < K; k0 += 64) {
        __syncthreads();
        #pragma unroll
        for (int t = 0; t < 4; ++t) {
            const int rb = (t << 5) + (wave << 3);
            GLDS16(A + (size_t)(m0 + rb + grow) * K + k0 + gcolk, &As[rb * 64]);
        }
        #pragma unroll
        for (int t = 0; t < NT / 32; ++t) {
            const int rb = (t << 5) + (wave << 3);
            GLDS16(Bt + (size_t)(n0 + rb + grow) * K + k0 + gcolk, &Bs[rb * 64]);
        }
        __syncthreads();
        #pragma unroll
        for (int h = 0; h < 2; ++h) {
            const int sw = (((h << 2) + lg) ^ (l15 & 7)) << 3;
            bf16x8 af[4], bfr[JN];
            #pragma unroll
            for (int i = 0; i < 4; ++i)
                af[i] = *(const bf16x8*)&As[(wm + (i << 4) + l15) * 64 + sw];
            #pragma unroll
            for (int j = 0; j < JN; ++j)
                bfr[j] = *(const bf16x8*)&Bs[(wn + (j << 4) + l15) * 64 + sw];
            #pragma unroll
            for (int i = 0; i < 4; ++i)
                #pragma unroll
                for (int j = 0; j < JN; ++j)
                    acc[i][j] = __builtin_amdgcn_mfma_f32_16x16x32_bf16(
                        af[i], bfr[j], acc[i][j], 0, 0, 0);
        }
    }

    if constexpr (EPI == 3) {
        if (n0 >= 1024) {          // V: transpose [n][m] via LDS, b128 writes
            __syncthreads();
            unsigned short* Tr = smem;
            #pragma unroll
            for (int i = 0; i < 4; ++i)
                #pragma unroll
                for (int j = 0; j < JN; ++j)
                    #pragma unroll
                    for (int r = 0; r < 4; ++r)
                        Tr[(wn + (j << 4) + l15) * TR + wm + (i << 4) + (lg << 2) + r]
                            = f2bf(acc[i][j][r]);
            __syncthreads();
            const int bb = m0 >> 10, s0 = m0 & 1023;
            #pragma unroll
            for (int it = 0; it < 8; ++it) {
                const int idx = (it << 8) + tid;
                const int ln = idx >> 4, lmc = (idx & 15) << 3;
                const int gcol = n0 - 1024 + ln;
                const int head = gcol >> 6, dh = gcol & 63;
                *(bf16x8*)((unsigned short*)Cv2 +
                    (size_t)((((bb << 3) + head) << 6) + dh) * 1024 + s0 + lmc) =
                    *(const bf16x8*)&Tr[ln * TR + lmc];
            }
            return;
        }
    }

    const float qsc = 0.125f * 1.44269504f;   // fold 1/sqrt(DH)*log2(e) into q
    const int crow0 = m0 + wm + (lg << 2);
    const int ccol0 = n0 + wn + l15;
    #pragma unroll
    for (int i = 0; i < 4; ++i)
        #pragma unroll
        for (int j = 0; j < JN; ++j)
            #pragma unroll
            for (int r = 0; r < 4; ++r) {
                const int row = crow0 + (i << 4) + r;
                const int col = ccol0 + (j << 4);
                float v = acc[i][j][r];
                if (EPI == 3) {
                    if (n0 < 512) v *= qsc;
                    ((unsigned short*)Cv)[(size_t)row * 1024 + col] = f2bf(v);
                } else {
                    if (EPI == 1) v = v / (1.0f + expf(-v));
                    ((unsigned short*)Cv)[(size_t)row * N + col] = f2bf(v);
                }
            }
}

// ---------------- MFMA flash attention, DH=64, 128-q blocks --------------
// Transposed scores: S^T = K Q^T (A=K-frag, B=Q-frag), so each lane owns
// q = lane&15 and 4 CONTIGUOUS keys per register quad -> P staged with
// ds_write_b64 (8 per wave-subtile vs 32 b16), l is one scalar per lane.
// Scores pre-scaled to log2 domain (q * 0.125*log2e); exp2 softmax without
// max-subtraction; V fragments cached in registers.
__global__ __launch_bounds__(256) void attn_mfma(
    const unsigned short* __restrict__ qk,   // [8192][1024] bf16, q' | k
    const unsigned short* __restrict__ vT,   // [64 bh][64 dh][1024 s] bf16
    const float* __restrict__ maskadd,       // 0 or -1e30 per token
    unsigned short* __restrict__ o)          // [8192][512] bf16
{
    constexpr int PST = 132;
    __shared__ unsigned short Ks[2][128][32];
    __shared__ unsigned short Vs[4][64][32];
    __shared__ unsigned short Ps[4][16][PST];  // [wave][q][key]
    __shared__ float Madd[128];
    const int tid = threadIdx.x;
    const int wave = tid >> 6, lane = tid & 63;
    const int b  = blockIdx.x & 7;
    const int hh = (blockIdx.x >> 3) & 7;
    const int qt = blockIdx.x >> 6;
    const int q0 = qt << 7;
    const int l15 = lane & 15, lg = lane >> 4;
    const int srow = lane >> 2;
    const int scol = (lane & 3) << 3;

    #pragma unroll
    for (int t = 0; t < 2; ++t)
        #pragma unroll
        for (int p = 0; p < 2; ++p)
            GLDS16(qk + (size_t)((b << 10) + q0 + (t << 6) + (wave << 4) + srow) * 1024
                      + (hh << 6) + (p << 5) + scol,
                   &Ks[p][(t << 6) + (wave << 4)][0]);
    __syncthreads();
    bf16x8 qf[2][2];
    #pragma unroll
    for (int s = 0; s < 2; ++s)
        #pragma unroll
        for (int p = 0; p < 2; ++p)
            qf[s][p] = *(const bf16x8*)&Ks[p][(s << 6) + (wave << 4) + l15][lg << 3];

    f32x4 oacc[2][4] = {};
    float l_s[2] = {0.f, 0.f};

    for (int kt = 0; kt < 8; ++kt) {
        const int k0 = kt << 7;
        __syncthreads();
        #pragma unroll
        for (int t = 0; t < 2; ++t)
            #pragma unroll
            for (int p = 0; p < 2; ++p)
                GLDS16(qk + (size_t)((b << 10) + k0 + (t << 6) + (wave << 4) + srow) * 1024
                          + 512 + (hh << 6) + (p << 5) + scol,
                       &Ks[p][(t << 6) + (wave << 4)][0]);
        #pragma unroll
        for (int kp = 0; kp < 4; ++kp)
            GLDS16(vT + (size_t)((((b << 3) + hh) << 6) + (wave << 4) + srow) * 1024
                      + k0 + (kp << 5) + scol,
                   &Vs[kp][wave << 4][0]);
        if (tid < 128) Madd[tid] = maskadd[(b << 10) + k0 + tid];
        __syncthreads();

        // S^T = K Q^T : C[m=key][n=q]; sacc[s][j][r] = S(key=(j<<4)+(lg<<2)+r, q=l15)
        f32x4 sacc[2][8] = {};
        #pragma unroll
        for (int j = 0; j < 8; ++j) {
            const bf16x8 kf0 = *(const bf16x8*)&Ks[0][(j << 4) + l15][lg << 3];
            const bf16x8 kf1 = *(const bf16x8*)&Ks[1][(j << 4) + l15][lg << 3];
            #pragma unroll
            for (int s = 0; s < 2; ++s) {
                sacc[s][j] = __builtin_amdgcn_mfma_f32_16x16x32_bf16(kf0, qf[s][0], sacc[s][j], 0, 0, 0);
                sacc[s][j] = __builtin_amdgcn_mfma_f32_16x16x32_bf16(kf1, qf[s][1], sacc[s][j], 0, 0, 0);
            }
        }

        // cache V fragments (reused by both q-subtiles)
        bf16x8 vf[4][4];
        #pragma unroll
        for (int kp = 0; kp < 4; ++kp)
            #pragma unroll
            for (int j = 0; j < 4; ++j)
                vf[kp][j] = *(const bf16x8*)&Vs[kp][(j << 4) + l15][lg << 3];

        // mask quads (keys contiguous per register quad)
        float4 ma4[8];
        #pragma unroll
        for (int j = 0; j < 8; ++j)
            ma4[j] = *(const float4*)&Madd[(j << 4) + (lg << 2)];

        #pragma unroll
        for (int s = 0; s < 2; ++s) {
            #pragma unroll
            for (int j = 0; j < 8; ++j) {
                const float p0 = exp2f(sacc[s][j][0] + ma4[j].x);
                const float p1 = exp2f(sacc[s][j][1] + ma4[j].y);
                const float p2 = exp2f(sacc[s][j][2] + ma4[j].z);
                const float p3 = exp2f(sacc[s][j][3] + ma4[j].w);
                l_s[s] += (p0 + p1) + (p2 + p3);
                ushort4 pk;
                pk.x = f2bf_fast(p0); pk.y = f2bf_fast(p1);
                pk.z = f2bf_fast(p2); pk.w = f2bf_fast(p3);
                *(ushort4*)&Ps[wave][l15][(j << 4) + (lg << 2)] = pk;
            }
            __asm__ volatile("s_waitcnt lgkmcnt(0)" ::: "memory");
            #pragma unroll
            for (int kp = 0; kp < 4; ++kp) {
                const bf16x8 pa = *(const bf16x8*)&Ps[wave][l15][(kp << 5) + (lg << 3)];
                #pragma unroll
                for (int j = 0; j < 4; ++j)
                    oacc[s][j] = __builtin_amdgcn_mfma_f32_16x16x32_bf16(pa, vf[kp][j], oacc[s][j], 0, 0, 0);
            }
            __asm__ volatile("s_waitcnt lgkmcnt(0)" ::: "memory");  // pa reads done before s=1 overwrites
        }
    }

    // l lives per-lane at q=l15: reduce the 4 lane-groups, then invert
    #pragma unroll
    for (int s = 0; s < 2; ++s) {
        float l = l_s[s];
        l += __shfl_xor(l, 16, 64);
        l += __shfl_xor(l, 32, 64);
        l_s[s] = 1.0f / l;
    }
    #pragma unroll
    for (int s = 0; s < 2; ++s) {
        float inv[4];
        #pragma unroll
        for (int r = 0; r < 4; ++r)
            inv[r] = __shfl(l_s[s], (lg << 2) + r, 64);   // lane (lg<<2)+r has q=(lg<<2)+r
        const int tokr = (b << 10) + q0 + (s << 6) + (wave << 4) + (lg << 2);
        #pragma unroll
        for (int j = 0; j < 4; ++j)
            #pragma unroll
            for (int r = 0; r < 4; ++r)
                o[(size_t)(tokr + r) * 512 + (hh << 6) + (j << 4) + l15] =
                    f2bf(oacc[s][j][r] * inv[r]);
    }
}

// ---------------- fused final layernorm + masked mean pool ----------------
__global__ __launch_bounds__(256) void pool_ln(
    const unsigned short* __restrict__ hbf, const float* __restrict__ notpad,
    const float* __restrict__ gf, const float* __restrict__ bfp,
    float* __restrict__ pooled, float* __restrict__ counts)
{
    __shared__ float sh[512];
    const int b = blockIdx.y, s0 = blockIdx.x << 5;
    const int wave = threadIdx.x >> 6, lane = threadIdx.x & 63;
    const int d0 = lane << 3;
    float gg[8], bb[8];
    ld4(gg, gf + d0); ld4(gg + 4, gf + d0 + 4);
    ld4(bb, bfp + d0); ld4(bb + 4, bfp + d0 + 4);
    float accv[8] = {};
    for (int t = 0; t < 8; ++t) {
        const int tok = (b << 10) + s0 + (wave << 3) + t;
        const float w = notpad[tok];
        const bf16x8 hv = *(const bf16x8*)(hbf + (size_t)tok * Dc + d0);
        float v[8], sum = 0.f, sumsq = 0.f;
        #pragma unroll
        for (int j = 0; j < 8; ++j) {
            v[j] = bf2f_s(hv[j]); sum += v[j]; sumsq += v[j] * v[j];
        }
        #pragma unroll
        for (int m = 1; m < 64; m <<= 1) {
            sum   += __shfl_xor(sum, m, 64);
            sumsq += __shfl_xor(sumsq, m, 64);
        }
        const float mu = sum * (1.0f / Dc);
        const float rstd = rsqrtf(sumsq * (1.0f / Dc) - mu * mu + 1e-5f);
        #pragma unroll
        for (int j = 0; j < 8; ++j)
            accv[j] = fmaf(w, (v[j] - mu) * rstd * gg[j] + bb[j], accv[j]);
    }
    sh[threadIdx.x] = 0.f; sh[threadIdx.x + 256] = 0.f;
    __syncthreads();
    #pragma unroll
    for (int j = 0; j < 8; ++j) atomicAdd(&sh[d0 + j], accv[j]);
    __syncthreads();
    atomicAdd(&pooled[b * Dc + threadIdx.x], sh[threadIdx.x]);
    atomicAdd(&pooled[b * Dc + 256 + threadIdx.x], sh[threadIdx.x + 256]);
    if (threadIdx.x < 32) {
        float w = notpad[(b << 10) + s0 + threadIdx.x];
        #pragma unroll
        for (int m = 1; m < 32; m <<= 1) w += __shfl_xor(w, m, 64);
        if (threadIdx.x == 0) atomicAdd(&counts[b], w);
    }
}

// ---------------- final tiny GEMV ----------------------------------------
__global__ void out_kernel(
    const float* __restrict__ pooled, const float* __restrict__ counts,
    const float* __restrict__ Wout, const float* __restrict__ bout,
    float* __restrict__ out)
{
    const int bo = blockIdx.x;
    const int b = bo / OUTc, oc = bo % OUTc;
    const int lane = threadIdx.x;
    float acc = 0.f;
    for (int d = lane; d < Dc; d += 64)
        acc = fmaf(pooled[b * Dc + d], Wout[(size_t)d * OUTc + oc], acc);
    #pragma unroll
    for (int m = 1; m < 64; m <<= 1) acc += __shfl_xor(acc, m, 64);
    if (lane == 0) out[b * OUTc + oc] = acc / (counts[b] + 1e-8f) + bout[oc];
}

} // namespace

extern "C" void kernel_launch(void* const* d_in, const int* in_sizes, int n_in,
                              void* d_out, int out_size, void* d_ws, size_t ws_size,
                              hipStream_t stream)
{
    (void)in_sizes; (void)n_in; (void)out_size; (void)ws_size;
    const float* x     = (const float*)d_in[0];
    const float* Wproj = (const float*)d_in[1];
    const float* bproj = (const float*)d_in[2];
    const float* gp    = (const float*)d_in[3];
    const float* bp    = (const float*)d_in[4];
    const float* Wq    = (const float*)d_in[5];
    const float* Wk    = (const float*)d_in[6];
    const float* Wv    = (const float*)d_in[7];
    const float* Wo    = (const float*)d_in[8];
    const float* g1    = (const float*)d_in[9];
    const float* b1    = (const float*)d_in[10];
    const float* W1    = (const float*)d_in[11];
    const float* W2    = (const float*)d_in[12];
    const float* g2    = (const float*)d_in[13];
    const float* b2    = (const float*)d_in[14];
    const float* gf    = (const float*)d_in[15];
    const float* bf    = (const float*)d_in[16];
    const float* Wout  = (const float*)d_in[17];
    const float* bout  = (const float*)d_in[18];
    float* out = (float*)d_out;

    const size_t MiB = 1u << 20;
    char* base = (char*)d_ws;
    unsigned short* h_bf    = (unsigned short*)(base);              // 8 MiB
    unsigned short* qk_act  = (unsigned short*)(base + 24 * MiB);   // 16 MiB [8192][1024]
    unsigned short* vT      = (unsigned short*)(base + 40 * MiB);   // 8 MiB [64][64][1024]
    unsigned short* ob_bf   = (unsigned short*)(base + 48 * MiB);   // 8 MiB [8192][512]
    unsigned short* bufB_bf = (unsigned short*)(base + 56 * MiB);   // 8 MiB [8192][512]
    unsigned short* ffa_bf  = (unsigned short*)(base + 24 * MiB);   // 32 MiB (aliases qk/vT/ob)
    unsigned short* qkvT    = (unsigned short*)(base + 72 * MiB);   // 6 MiB
    unsigned short* WoT     = (unsigned short*)(base + 78 * MiB);   // 2 MiB
    unsigned short* W1T     = (unsigned short*)(base + 80 * MiB);   // 8 MiB
    unsigned short* W2T     = (unsigned short*)(base + 88 * MiB);   // 8 MiB
    float*          notpad  = (float*)(base + 96 * MiB);            // 32 KiB
    float*          maskadd = notpad + 8192;                        // 32 KiB
    float*          pooled  = maskadd + 8192;
    float*          counts  = pooled + Bc * Dc;

    const int M = Bc * Sc;       // 8192
    const int MT = M / 128;      // 64 m-tiles (multiple of 8 -> XCD swizzle valid)

    castAll<<<3072, 256, 0, stream>>>(Wq, Wk, Wv, Wo, W1, W2, qkvT, WoT, W1T, W2T);
    proj_pe_ln<<<M / 4, 256, 0, stream>>>(x, Wproj, bproj, gp, bp, h_bf, notpad, maskadd);

    for (int l = 0; l < Lc; ++l) {
        gemm_bf16<3, 128><<<(QS / 128) * MT, 256, 0, stream>>>(
            h_bf, qkvT + (size_t)l * QS * 512, qk_act, vT, M, QS, 512);
        attn_mfma<<<Bc * Hc * (Sc / 128), 256, 0, stream>>>(qk_act, vT, maskadd, ob_bf);
        gemm_bf16<2, 64><<<(512 / 64) * MT, 256, 0, stream>>>(
            ob_bf, WoT + (size_t)l * 512 * 512, bufB_bf, nullptr, M, 512, 512);
        add_ln<<<M / 4, 256, 0, stream>>>(h_bf, bufB_bf, g1 + (size_t)l * Dc, b1 + (size_t)l * Dc, h_bf);
        gemm_bf16<1, 128><<<(FFc / 128) * MT, 256, 0, stream>>>(
            h_bf, W1T + (size_t)l * FFc * 512, ffa_bf, nullptr, M, FFc, 512);
        gemm_bf16<2, 64><<<(512 / 64) * MT, 256, 0, stream>>>(
            ffa_bf, W2T + (size_t)l * 512 * FFc, bufB_bf, nullptr, M, 512, FFc);
        add_ln<<<M / 4, 256, 0, stream>>>(h_bf, bufB_bf, g2 + (size_t)l * Dc, b2 + (size_t)l * Dc, h_bf);
    }

    hipMemsetAsync(pooled, 0, (size_t)(Bc * Dc + Bc) * sizeof(float), stream);
    pool_ln<<<dim3(Sc / 32, Bc), 256, 0, stream>>>(h_bf, notpad, gf, bf, pooled, counts);
    out_kernel<<<Bc * OUTc, 64, 0, stream>>>(pooled, counts, Wout, bout, out);
}